// Round 1
// baseline (408.896 us; speedup 1.0000x reference)
//
#include <hip/hip_runtime.h>
#include <math.h>

// Problem constants
#define NB     32
#define DIM    64
#define HH     64
#define WW     64
#define HW     (HH * WW)            // 4096
#define DHW    (DIM * HW)           // 262144
#define N_ROWS (NB * HW)            // 131072
#define K_CODES 1024

#define Q_ELEMS  (NB * DIM * HW)    // 8388608
#define LOSS_OFF Q_ELEMS            // 8388608
#define IDX_OFF  (Q_ELEMS + 1)      // 8388609

#define MAIN_BLOCKS (N_ROWS / 256)  // 512

// ws layout (floats): [0..512) per-block partial loss sums, [512..1536) e2 table

// ---------------------------------------------------------------------------
// Kernel 1: e2[k] = sum_d emb[k][d]^2, replicating numpy pairwise-8 order.
__global__ void vq_prep(const float* __restrict__ emb, float* __restrict__ e2out) {
    int k = blockIdx.x * blockDim.x + threadIdx.x;
    if (k >= K_CODES) return;
    const float* e = emb + k * DIM;
    float r[8];
#pragma unroll
    for (int j = 0; j < 8; ++j) r[j] = __fmul_rn(e[j], e[j]);
#pragma unroll
    for (int m = 1; m < 8; ++m) {
#pragma unroll
        for (int j = 0; j < 8; ++j)
            r[j] = __fadd_rn(r[j], __fmul_rn(e[8 * m + j], e[8 * m + j]));
    }
    float s01 = __fadd_rn(r[0], r[1]);
    float s23 = __fadd_rn(r[2], r[3]);
    float s45 = __fadd_rn(r[4], r[5]);
    float s67 = __fadd_rn(r[6], r[7]);
    e2out[k] = __fadd_rn(__fadd_rn(s01, s23), __fadd_rn(s45, s67));
}

// ---------------------------------------------------------------------------
// Kernel 2: per row n: argmin_k ( (x2 + e2[k]) + (-2 * dot(x, e_k)) ),
// write quantized_st, index (as float), and per-block loss partial sum.
__global__ __launch_bounds__(256) void vq_main(const float* __restrict__ in,
                                               const float* __restrict__ emb,
                                               const float* __restrict__ e2,
                                               float* __restrict__ out,
                                               float* __restrict__ partial) {
    const int n  = blockIdx.x * 256 + threadIdx.x;
    const int b  = n >> 12;        // n / HW
    const int hw = n & (HW - 1);   // n % HW

    const float* xin = in + (size_t)b * DHW + hw;
    float x[DIM];
#pragma unroll
    for (int d = 0; d < DIM; ++d) x[d] = xin[d * HW];

    // x2 = numpy pairwise-8 sum of x[d]^2 (products rounded separately)
    float r[8];
#pragma unroll
    for (int j = 0; j < 8; ++j) r[j] = __fmul_rn(x[j], x[j]);
#pragma unroll
    for (int m = 1; m < 8; ++m) {
#pragma unroll
        for (int j = 0; j < 8; ++j)
            r[j] = __fadd_rn(r[j], __fmul_rn(x[8 * m + j], x[8 * m + j]));
    }
    const float x2 = __fadd_rn(
        __fadd_rn(__fadd_rn(r[0], r[1]), __fadd_rn(r[2], r[3])),
        __fadd_rn(__fadd_rn(r[4], r[5]), __fadd_rn(r[6], r[7])));

    float best = INFINITY;
    int   bidx = 0;
    for (int k = 0; k < K_CODES; ++k) {
        const float* ek = emb + k * DIM;   // wave-uniform -> scalar loads
        float dot = 0.0f;
#pragma unroll
        for (int d = 0; d < DIM; ++d) dot = __fmaf_rn(x[d], ek[d], dot);
        // dist = (x2 + e2k) + (-2*dot); -2*dot is exact (pow2 scale)
        float dist = __fadd_rn(__fadd_rn(x2, e2[k]), -2.0f * dot);
        if (dist < best) { best = dist; bidx = k; }   // strict < : first occurrence
    }

    // Outputs
    const float* q   = emb + bidx * DIM;
    float* qout      = out + (size_t)b * DHW + hw;
    float lsum = 0.0f;
#pragma unroll
    for (int d = 0; d < DIM; ++d) {
        float qd   = q[d];
        float diff = __fsub_rn(qd, x[d]);
        lsum = __fadd_rn(lsum, __fmul_rn(diff, diff));
        // straight-through: x + (q - x), replicated op order
        qout[d * HW] = __fadd_rn(x[d], diff);
    }
    out[IDX_OFF + n] = (float)bidx;

    // Deterministic block reduction of lsum (4 waves of 64)
    __shared__ float red[4];
#pragma unroll
    for (int off = 32; off > 0; off >>= 1)
        lsum += __shfl_down(lsum, off, 64);
    const int lane = threadIdx.x & 63;
    const int wid  = threadIdx.x >> 6;
    if (lane == 0) red[wid] = lsum;
    __syncthreads();
    if (threadIdx.x == 0) {
        float s = ((red[0] + red[1]) + (red[2] + red[3]));
        partial[blockIdx.x] = s;
    }
}

// ---------------------------------------------------------------------------
// Kernel 3: deterministic tree reduce of 512 partials -> loss scalar.
__global__ __launch_bounds__(256) void vq_final(const float* __restrict__ partial,
                                                float* __restrict__ out) {
    __shared__ float s[256];
    int t = threadIdx.x;
    s[t] = partial[t] + partial[t + 256];
    __syncthreads();
    for (int off = 128; off > 0; off >>= 1) {
        if (t < off) s[t] += s[t + off];
        __syncthreads();
    }
    if (t == 0) out[LOSS_OFF] = 0.25f * s[0] / (float)Q_ELEMS;
}

// ---------------------------------------------------------------------------
extern "C" void kernel_launch(void* const* d_in, const int* in_sizes, int n_in,
                              void* d_out, int out_size, void* d_ws, size_t ws_size,
                              hipStream_t stream) {
    const float* in  = (const float*)d_in[0];
    const float* emb = (const float*)d_in[1];
    float* out = (float*)d_out;
    float* ws  = (float*)d_ws;
    float* partial = ws;        // 512 floats
    float* e2      = ws + 512;  // 1024 floats

    vq_prep<<<4, 256, 0, stream>>>(emb, e2);
    vq_main<<<MAIN_BLOCKS, 256, 0, stream>>>(in, emb, e2, out, partial);
    vq_final<<<1, 256, 0, stream>>>(partial, out);
}

// Round 2
// 155.895 us; speedup vs baseline: 2.6229x; 2.6229x over previous
//
#include <hip/hip_runtime.h>
#include <math.h>

// Problem constants
#define NB     32
#define DIM    64
#define HW     4096
#define DHW    (DIM * HW)           // 262144
#define N_ROWS (NB * HW)            // 131072
#define K_CODES 1024

#define Q_ELEMS  (NB * DIM * HW)    // 8388608
#define LOSS_OFF Q_ELEMS
#define IDX_OFF  (Q_ELEMS + 1)

#define ROWS       64               // rows per block
#define MAIN_BLOCKS (N_ROWS / ROWS) // 2048
#define MARGIN     6e-3f
#define CAND_CAP   64

typedef __attribute__((ext_vector_type(8))) short short8;
typedef __attribute__((ext_vector_type(4))) float f32x4;

// ws layout (floats): [0..2048) loss partials, [2048..3072) e2 table,
// then 65536 ushorts (128KB) of bf16 codebook.

__device__ __forceinline__ ushort f2bf_rne(float f) {
    unsigned u = __float_as_uint(f);
    u = (u + 0x7FFFu + ((u >> 16) & 1u)) >> 16;
    return (ushort)u;
}

// ---------------------------------------------------------------------------
// Prep: e2[k] (numpy pairwise-8 order, also used by exact rescore) + bf16 codebook.
__global__ void vq_prep(const float* __restrict__ emb, float* __restrict__ e2out,
                        ushort* __restrict__ ebf) {
    int k = blockIdx.x * blockDim.x + threadIdx.x;
    if (k >= K_CODES) return;
    const float* e = emb + k * DIM;
    float r[8];
#pragma unroll
    for (int j = 0; j < 8; ++j) r[j] = __fmul_rn(e[j], e[j]);
#pragma unroll
    for (int m = 1; m < 8; ++m) {
#pragma unroll
        for (int j = 0; j < 8; ++j)
            r[j] = __fadd_rn(r[j], __fmul_rn(e[8 * m + j], e[8 * m + j]));
    }
    e2out[k] = __fadd_rn(__fadd_rn(__fadd_rn(r[0], r[1]), __fadd_rn(r[2], r[3])),
                         __fadd_rn(__fadd_rn(r[4], r[5]), __fadd_rn(r[6], r[7])));
    ushort* eb = ebf + k * DIM;
#pragma unroll
    for (int d = 0; d < DIM; ++d) eb[d] = f2bf_rne(e[d]);
}

// ---------------------------------------------------------------------------
// Main: per block 64 rows x 1024 codes.
//  Phase A: stage X tile (f32 + XOR-swizzled bf16) in LDS, x2 per row.
//  Pass 1:  MFMA approx scores, per-row min.
//  Pass 2:  recompute (bit-identical), collect candidates within MARGIN.
//  Pass 3:  exact fp32 rescore (replicated np op order), outputs + loss.
__global__ __launch_bounds__(256, 3) void vq_main(
    const float* __restrict__ in, const float* __restrict__ emb,
    const float* __restrict__ e2, const ushort* __restrict__ ebf,
    float* __restrict__ out, float* __restrict__ partial)
{
    __shared__ __align__(16) float  Xf[ROWS][DIM + 1];   // 16.6 KB
    __shared__ __align__(16) ushort Xb[ROWS * DIM];      // 8 KB, swizzled bf16
    __shared__ float x2s[ROWS];
    __shared__ float wmin[4][ROWS];
    __shared__ float minap[ROWS];
    __shared__ unsigned cnt[ROWS];
    __shared__ ushort cand[ROWS][CAND_CAP];              // 8 KB
    __shared__ __align__(16) float Qf[DIM][ROWS];        // 16 KB, [d][r]
    __shared__ int idxs[ROWS];

    const int t   = threadIdx.x;
    const int b   = blockIdx.x >> 6;
    const int hw0 = (blockIdx.x & 63) * ROWS;
    const long n0 = (long)b * HW + hw0;
    const float* inb = in + (size_t)b * DHW + hw0;

    // ---- Phase A: stage X --------------------------------------------------
    {
        const int c16 = t & 15;   // 16 lanes cover one 64-wide d-line (float4)
        const int dl  = t >> 4;   // d line base
#pragma unroll
        for (int i = 0; i < 4; ++i) {
            const int d = dl + 16 * i;
            const float4 v = *(const float4*)(inb + (size_t)d * HW + c16 * 4);
            const float vv[4] = {v.x, v.y, v.z, v.w};
#pragma unroll
            for (int c = 0; c < 4; ++c) {
                const int r = c16 * 4 + c;
                Xf[r][d] = vv[c];
                const int g = (d >> 3) ^ (r & 7);          // XOR swizzle (G4)
                Xb[r * DIM + g * 8 + (d & 7)] = f2bf_rne(vv[c]);
            }
        }
        if (t < ROWS) cnt[t] = 0;
    }
    __syncthreads();

    // x2 per row (numpy pairwise-8, same as passing round-1 kernel)
    if (t < ROWS) {
        const float* xr = Xf[t];
        float r8[8];
#pragma unroll
        for (int j = 0; j < 8; ++j) r8[j] = __fmul_rn(xr[j], xr[j]);
#pragma unroll
        for (int m = 1; m < 8; ++m) {
#pragma unroll
            for (int j = 0; j < 8; ++j)
                r8[j] = __fadd_rn(r8[j], __fmul_rn(xr[8 * m + j], xr[8 * m + j]));
        }
        x2s[t] = __fadd_rn(__fadd_rn(__fadd_rn(r8[0], r8[1]), __fadd_rn(r8[2], r8[3])),
                           __fadd_rn(__fadd_rn(r8[4], r8[5]), __fadd_rn(r8[6], r8[7])));
    }

    // ---- A fragments (constant per wave across all code chunks) ------------
    const int w   = t >> 6;
    const int l   = t & 63;
    const int lg  = l >> 4;    // lane group
    const int l15 = l & 15;
    short8 afr[4][2];
#pragma unroll
    for (int rfi = 0; rfi < 4; ++rfi) {
#pragma unroll
        for (int kf = 0; kf < 2; ++kf) {
            const int r  = rfi * 16 + l15;     // A row = X row
            const int kg = kf * 4 + lg;        // element-group index (k>>3)
            const int g  = kg ^ (r & 7);       // undo swizzle
            afr[rfi][kf] = *(const short8*)&Xb[r * DIM + g * 8];
        }
    }

    // ---- Pass 1: per-row min of approx score -------------------------------
    float vmin[4][4];
#pragma unroll
    for (int i = 0; i < 4; ++i)
#pragma unroll
        for (int j = 0; j < 4; ++j) vmin[i][j] = INFINITY;

    for (int iter = 0; iter < 4; ++iter) {
        const int cw = iter * 256 + w * 64;
#pragma unroll
        for (int cfi = 0; cfi < 4; ++cfi) {
            const int code = cw + cfi * 16 + l15;          // B col = code
            const short8 b0 = *(const short8*)(ebf + code * DIM + lg * 8);
            const short8 b1 = *(const short8*)(ebf + code * DIM + 32 + lg * 8);
            const float e2c = e2[code];
#pragma unroll
            for (int rfi = 0; rfi < 4; ++rfi) {
                f32x4 c = {0.f, 0.f, 0.f, 0.f};
                c = __builtin_amdgcn_mfma_f32_16x16x32_bf16(afr[rfi][0], b0, c, 0, 0, 0);
                c = __builtin_amdgcn_mfma_f32_16x16x32_bf16(afr[rfi][1], b1, c, 0, 0, 0);
#pragma unroll
                for (int j = 0; j < 4; ++j) {
                    const float av = __fmaf_rn(-2.0f, c[j], e2c);
                    vmin[rfi][j] = fminf(vmin[rfi][j], av);
                }
            }
        }
    }
    // reduce min across the 16 lanes sharing a row set
#pragma unroll
    for (int m = 1; m < 16; m <<= 1) {
#pragma unroll
        for (int rfi = 0; rfi < 4; ++rfi)
#pragma unroll
            for (int j = 0; j < 4; ++j)
                vmin[rfi][j] = fminf(vmin[rfi][j], __shfl_xor(vmin[rfi][j], m, 64));
    }
    if (l15 == 0) {
#pragma unroll
        for (int rfi = 0; rfi < 4; ++rfi)
#pragma unroll
            for (int j = 0; j < 4; ++j)
                wmin[w][rfi * 16 + lg * 4 + j] = vmin[rfi][j];
    }
    __syncthreads();
    if (t < ROWS)
        minap[t] = fminf(fminf(wmin[0][t], wmin[1][t]),
                         fminf(wmin[2][t], wmin[3][t])) + MARGIN;
    __syncthreads();

    // ---- Pass 2: candidate collection --------------------------------------
    float bound[4][4];
#pragma unroll
    for (int rfi = 0; rfi < 4; ++rfi)
#pragma unroll
        for (int j = 0; j < 4; ++j)
            bound[rfi][j] = minap[rfi * 16 + lg * 4 + j];

    for (int iter = 0; iter < 4; ++iter) {
        const int cw = iter * 256 + w * 64;
#pragma unroll
        for (int cfi = 0; cfi < 4; ++cfi) {
            const int code = cw + cfi * 16 + l15;
            const short8 b0 = *(const short8*)(ebf + code * DIM + lg * 8);
            const short8 b1 = *(const short8*)(ebf + code * DIM + 32 + lg * 8);
            const float e2c = e2[code];
#pragma unroll
            for (int rfi = 0; rfi < 4; ++rfi) {
                f32x4 c = {0.f, 0.f, 0.f, 0.f};
                c = __builtin_amdgcn_mfma_f32_16x16x32_bf16(afr[rfi][0], b0, c, 0, 0, 0);
                c = __builtin_amdgcn_mfma_f32_16x16x32_bf16(afr[rfi][1], b1, c, 0, 0, 0);
#pragma unroll
                for (int j = 0; j < 4; ++j) {
                    const float av = __fmaf_rn(-2.0f, c[j], e2c);
                    if (av <= bound[rfi][j]) {
                        const int row = rfi * 16 + lg * 4 + j;
                        const unsigned slot = atomicAdd(&cnt[row], 1u);
                        if (slot < CAND_CAP) cand[row][slot] = (ushort)code;
                    }
                }
            }
        }
    }
    __syncthreads();

    // ---- Pass 3: exact fp32 rescore (replicated np order) ------------------
    if (t < ROWS) {
        const int r = t;
        float x[DIM];
#pragma unroll
        for (int d = 0; d < DIM; ++d) x[d] = Xf[r][d];
        const float x2v = x2s[r];
        int nc = (int)cnt[r];
        if (nc > CAND_CAP) nc = CAND_CAP;
        float best = INFINITY;
        int   bk   = K_CODES;
        for (int ci = 0; ci < nc; ++ci) {
            const int k = cand[r][ci];
            const float* ek = emb + k * DIM;
            float dot = 0.0f;
#pragma unroll
            for (int d = 0; d < DIM; ++d) dot = __fmaf_rn(x[d], ek[d], dot);
            const float dist = __fadd_rn(__fadd_rn(x2v, e2[k]), -2.0f * dot);
            if (dist < best || (dist == best && k < bk)) { best = dist; bk = k; }
        }
        idxs[r] = bk;
        out[IDX_OFF + n0 + r] = (float)bk;
    }
    __syncthreads();

    // ---- stage quantized rows into LDS [d][r] ------------------------------
    {
        const int r  = t >> 2;
        const int dq = t & 3;
        const float* eq = emb + idxs[r] * DIM + dq * 16;
#pragma unroll
        for (int i = 0; i < 4; ++i) {
            const float4 v = *(const float4*)(eq + i * 4);
            const int d = dq * 16 + i * 4;
            Qf[d + 0][r] = v.x; Qf[d + 1][r] = v.y;
            Qf[d + 2][r] = v.z; Qf[d + 3][r] = v.w;
        }
    }
    __syncthreads();

    // ---- quantized_st writes (coalesced along hw) --------------------------
    {
        const int r  = t & 63;
        const int dg = t >> 6;
        float* ob = out + (size_t)b * DHW + hw0 + r;
#pragma unroll
        for (int i = 0; i < 16; ++i) {
            const int d = dg * 16 + i;
            const float xv = Xf[r][d];
            ob[(size_t)d * HW] = __fadd_rn(xv, __fsub_rn(Qf[d][r], xv));
        }
    }

    // ---- loss partial (wave 0) ---------------------------------------------
    if (t < ROWS) {
        const int r = t;
        float ls = 0.0f;
#pragma unroll
        for (int d = 0; d < DIM; ++d) {
            const float diff = __fsub_rn(Qf[d][r], Xf[r][d]);
            ls = __fadd_rn(ls, __fmul_rn(diff, diff));
        }
#pragma unroll
        for (int off = 32; off > 0; off >>= 1) ls += __shfl_down(ls, off, 64);
        if (t == 0) partial[blockIdx.x] = ls;
    }
}

// ---------------------------------------------------------------------------
__global__ __launch_bounds__(256) void vq_final(const float* __restrict__ partial,
                                                float* __restrict__ out) {
    __shared__ float s[256];
    const int t = threadIdx.x;
    float a = 0.0f;
#pragma unroll
    for (int i = 0; i < 8; ++i) a += partial[t + 256 * i];
    s[t] = a;
    __syncthreads();
    for (int off = 128; off > 0; off >>= 1) {
        if (t < off) s[t] += s[t + off];
        __syncthreads();
    }
    if (t == 0) out[LOSS_OFF] = 0.25f * s[0] / (float)Q_ELEMS;
}

// ---------------------------------------------------------------------------
extern "C" void kernel_launch(void* const* d_in, const int* in_sizes, int n_in,
                              void* d_out, int out_size, void* d_ws, size_t ws_size,
                              hipStream_t stream) {
    const float* in  = (const float*)d_in[0];
    const float* emb = (const float*)d_in[1];
    float* out = (float*)d_out;
    float* ws  = (float*)d_ws;
    float*  partial = ws;                       // 2048 floats
    float*  e2      = ws + 2048;                // 1024 floats
    ushort* ebf     = (ushort*)(ws + 3072);     // 65536 ushorts (128 KB)

    vq_prep<<<4, 256, 0, stream>>>(emb, e2, ebf);
    vq_main<<<MAIN_BLOCKS, 256, 0, stream>>>(in, emb, e2, ebf, out, partial);
    vq_final<<<1, 256, 0, stream>>>(partial, out);
}

// Round 3
// 147.907 us; speedup vs baseline: 2.7645x; 1.0540x over previous
//
#include <hip/hip_runtime.h>
#include <math.h>

// Problem constants
#define NB     32
#define DIM    64
#define HW     4096
#define DHW    (DIM * HW)           // 262144
#define N_ROWS (NB * HW)            // 131072
#define K_CODES 1024

#define Q_ELEMS  (NB * DIM * HW)    // 8388608
#define LOSS_OFF Q_ELEMS
#define IDX_OFF  (Q_ELEMS + 1)

#define ROWS       64               // rows per block
#define MAIN_BLOCKS (N_ROWS / ROWS) // 2048
#define MARGIN     6e-3f
#define CAND_CAP   64

typedef __attribute__((ext_vector_type(8))) short short8;
typedef __attribute__((ext_vector_type(4))) float f32x4;

// ws layout (floats): [0..2048) loss partials, [2048..3072) e2 table,
// then 65536 ushorts (128KB) of bf16 codebook.

__device__ __forceinline__ ushort f2bf_rne(float f) {
    unsigned u = __float_as_uint(f);
    u = (u + 0x7FFFu + ((u >> 16) & 1u)) >> 16;
    return (ushort)u;
}

// ---------------------------------------------------------------------------
// Prep: e2[k] (numpy pairwise-8 order, also used by exact rescore) + bf16 codebook.
__global__ void vq_prep(const float* __restrict__ emb, float* __restrict__ e2out,
                        ushort* __restrict__ ebf) {
    int k = blockIdx.x * blockDim.x + threadIdx.x;
    if (k >= K_CODES) return;
    const float* e = emb + k * DIM;
    float r[8];
#pragma unroll
    for (int j = 0; j < 8; ++j) r[j] = __fmul_rn(e[j], e[j]);
#pragma unroll
    for (int m = 1; m < 8; ++m) {
#pragma unroll
        for (int j = 0; j < 8; ++j)
            r[j] = __fadd_rn(r[j], __fmul_rn(e[8 * m + j], e[8 * m + j]));
    }
    e2out[k] = __fadd_rn(__fadd_rn(__fadd_rn(r[0], r[1]), __fadd_rn(r[2], r[3])),
                         __fadd_rn(__fadd_rn(r[4], r[5]), __fadd_rn(r[6], r[7])));
    ushort* eb = ebf + k * DIM;
#pragma unroll
    for (int d = 0; d < DIM; ++d) eb[d] = f2bf_rne(e[d]);
}

// ---------------------------------------------------------------------------
// Main: 64 rows x 1024 codes per block.
//  Stage X as [d][r] via global_load_lds; MFMA filter (2 passes) + exact rescore.
__global__ __launch_bounds__(256, 5) void vq_main(
    const float* __restrict__ in, const float* __restrict__ emb,
    const float* __restrict__ e2, const ushort* __restrict__ ebf,
    float* __restrict__ out, float* __restrict__ partial)
{
    __shared__ __align__(16) float Xf[DIM][ROWS];        // 16 KB, [d][r]
    __shared__ float x2s[ROWS];
    __shared__ float wmin[4][ROWS];
    __shared__ float minap[ROWS];
    __shared__ unsigned cnt[ROWS];
    __shared__ ushort cand[ROWS][CAND_CAP];              // 8 KB
    __shared__ int idxs[ROWS];
    __shared__ float lred[4];

    const int t   = threadIdx.x;
    const int w   = t >> 6;
    const int l   = t & 63;
    const int b   = blockIdx.x >> 6;
    const int hw0 = (blockIdx.x & 63) * ROWS;
    const long n0 = (long)b * HW + hw0;
    const float* inb = in + (size_t)b * DHW + hw0;

    // ---- Stage X[d][r] via async global->LDS (linear dest, zero conflicts) --
    {
        const int dl = l >> 4;            // d offset within 4-line packet
        const int c4 = (l & 15) * 4;      // hw offset (floats)
#pragma unroll
        for (int i = 0; i < 4; ++i) {
            const int d0 = w * 16 + i * 4;                 // wave-uniform
            const float* src = inb + (size_t)(d0 + dl) * HW + c4;
            __builtin_amdgcn_global_load_lds(
                (const __attribute__((address_space(1))) void*)src,
                (__attribute__((address_space(3))) void*)&Xf[d0][0],
                16, 0, 0);
        }
        if (t < ROWS) cnt[t] = 0;
    }
    __syncthreads();

    // ---- x2 per row (numpy pairwise-8, bit-identical to round-1 kernel) ----
    if (t < ROWS) {
        float r8[8];
#pragma unroll
        for (int j = 0; j < 8; ++j) {
            const float v = Xf[j][t];
            r8[j] = __fmul_rn(v, v);
        }
#pragma unroll
        for (int m = 1; m < 8; ++m) {
#pragma unroll
            for (int j = 0; j < 8; ++j) {
                const float v = Xf[8 * m + j][t];
                r8[j] = __fadd_rn(r8[j], __fmul_rn(v, v));
            }
        }
        x2s[t] = __fadd_rn(__fadd_rn(__fadd_rn(r8[0], r8[1]), __fadd_rn(r8[2], r8[3])),
                           __fadd_rn(__fadd_rn(r8[4], r8[5]), __fadd_rn(r8[6], r8[7])));
    }

    // ---- A fragments in registers (bf16, same f2bf_rne values as before) ---
    const int lg  = l >> 4;
    const int l15 = l & 15;
    short8 afr[4][2];
#pragma unroll
    for (int rfi = 0; rfi < 4; ++rfi) {
#pragma unroll
        for (int kf = 0; kf < 2; ++kf) {
            const int r  = rfi * 16 + l15;
            const int d0 = (kf * 4 + lg) * 8;
            short8 a;
#pragma unroll
            for (int j = 0; j < 8; ++j) a[j] = (short)f2bf_rne(Xf[d0 + j][r]);
            afr[rfi][kf] = a;
        }
    }

    // ---- Pass 1: per-row min of approx score -------------------------------
    float vmin[4][4];
#pragma unroll
    for (int i = 0; i < 4; ++i)
#pragma unroll
        for (int j = 0; j < 4; ++j) vmin[i][j] = INFINITY;

    for (int iter = 0; iter < 4; ++iter) {
        const int cw = iter * 256 + w * 64;
#pragma unroll
        for (int cfi = 0; cfi < 4; ++cfi) {
            const int code = cw + cfi * 16 + l15;
            const short8 b0 = *(const short8*)(ebf + code * DIM + lg * 8);
            const short8 b1 = *(const short8*)(ebf + code * DIM + 32 + lg * 8);
            const float e2c = e2[code];
#pragma unroll
            for (int rfi = 0; rfi < 4; ++rfi) {
                f32x4 c = {0.f, 0.f, 0.f, 0.f};
                c = __builtin_amdgcn_mfma_f32_16x16x32_bf16(afr[rfi][0], b0, c, 0, 0, 0);
                c = __builtin_amdgcn_mfma_f32_16x16x32_bf16(afr[rfi][1], b1, c, 0, 0, 0);
#pragma unroll
                for (int j = 0; j < 4; ++j) {
                    const float av = __fmaf_rn(-2.0f, c[j], e2c);
                    vmin[rfi][j] = fminf(vmin[rfi][j], av);
                }
            }
        }
    }
#pragma unroll
    for (int m = 1; m < 16; m <<= 1) {
#pragma unroll
        for (int rfi = 0; rfi < 4; ++rfi)
#pragma unroll
            for (int j = 0; j < 4; ++j)
                vmin[rfi][j] = fminf(vmin[rfi][j], __shfl_xor(vmin[rfi][j], m, 64));
    }
    if (l15 == 0) {
#pragma unroll
        for (int rfi = 0; rfi < 4; ++rfi)
#pragma unroll
            for (int j = 0; j < 4; ++j)
                wmin[w][rfi * 16 + lg * 4 + j] = vmin[rfi][j];
    }
    __syncthreads();
    if (t < ROWS)
        minap[t] = fminf(fminf(wmin[0][t], wmin[1][t]),
                         fminf(wmin[2][t], wmin[3][t])) + MARGIN;
    __syncthreads();

    // ---- Pass 2: candidate collection --------------------------------------
    float bound[4][4];
#pragma unroll
    for (int rfi = 0; rfi < 4; ++rfi)
#pragma unroll
        for (int j = 0; j < 4; ++j)
            bound[rfi][j] = minap[rfi * 16 + lg * 4 + j];

    for (int iter = 0; iter < 4; ++iter) {
        const int cw = iter * 256 + w * 64;
#pragma unroll
        for (int cfi = 0; cfi < 4; ++cfi) {
            const int code = cw + cfi * 16 + l15;
            const short8 b0 = *(const short8*)(ebf + code * DIM + lg * 8);
            const short8 b1 = *(const short8*)(ebf + code * DIM + 32 + lg * 8);
            const float e2c = e2[code];
#pragma unroll
            for (int rfi = 0; rfi < 4; ++rfi) {
                f32x4 c = {0.f, 0.f, 0.f, 0.f};
                c = __builtin_amdgcn_mfma_f32_16x16x32_bf16(afr[rfi][0], b0, c, 0, 0, 0);
                c = __builtin_amdgcn_mfma_f32_16x16x32_bf16(afr[rfi][1], b1, c, 0, 0, 0);
#pragma unroll
                for (int j = 0; j < 4; ++j) {
                    const float av = __fmaf_rn(-2.0f, c[j], e2c);
                    if (av <= bound[rfi][j]) {
                        const int row = rfi * 16 + lg * 4 + j;
                        const unsigned slot = atomicAdd(&cnt[row], 1u);
                        if (slot < CAND_CAP) cand[row][slot] = (ushort)code;
                    }
                }
            }
        }
    }
    __syncthreads();

    // ---- Exact fp32 rescore, 4 lanes per row (replicated np op order) ------
    {
        const int q = t & 3;
        const int r = t >> 2;
        int nc = (int)cnt[r];
        if (nc > CAND_CAP) nc = CAND_CAP;
        const float x2v = x2s[r];
        float best = INFINITY;
        int   bk   = K_CODES;
        for (int ci = q; ci < nc; ci += 4) {
            const int k = cand[r][ci];
            const float* ek = emb + k * DIM;
            float dot = 0.0f;
#pragma unroll
            for (int dd = 0; dd < DIM; dd += 4) {
                const float4 ev = *(const float4*)(ek + dd);
                dot = __fmaf_rn(Xf[dd + 0][r], ev.x, dot);
                dot = __fmaf_rn(Xf[dd + 1][r], ev.y, dot);
                dot = __fmaf_rn(Xf[dd + 2][r], ev.z, dot);
                dot = __fmaf_rn(Xf[dd + 3][r], ev.w, dot);
            }
            const float dist = __fadd_rn(__fadd_rn(x2v, e2[k]), -2.0f * dot);
            if (dist < best || (dist == best && k < bk)) { best = dist; bk = k; }
        }
#pragma unroll
        for (int m = 1; m < 4; m <<= 1) {
            const float ob = __shfl_xor(best, m, 64);
            const int   ok = __shfl_xor(bk,   m, 64);
            if (ob < best || (ob == best && ok < bk)) { best = ob; bk = ok; }
        }
        if (q == 0) {
            idxs[r] = bk;
            out[IDX_OFF + n0 + r] = (float)bk;
        }
    }
    __syncthreads();

    // ---- quantized_st writes + fused loss (all 256 threads) ----------------
    {
        const int r  = l;          // row = lane (coalesced stores)
        const int dg = w;          // wave covers 16 d-lines
        const float* eq = emb + idxs[r] * DIM + dg * 16;
        float* ob = out + (size_t)b * DHW + hw0 + r;
        float ls = 0.0f;
#pragma unroll
        for (int i = 0; i < 4; ++i) {
            const float4 qv = *(const float4*)(eq + i * 4);
            const float qa[4] = {qv.x, qv.y, qv.z, qv.w};
#pragma unroll
            for (int c2 = 0; c2 < 4; ++c2) {
                const int d = dg * 16 + i * 4 + c2;
                const float xv = Xf[d][r];
                const float df = __fsub_rn(qa[c2], xv);
                ls = __fadd_rn(ls, __fmul_rn(df, df));
                ob[(size_t)d * HW] = __fadd_rn(xv, df);
            }
        }
#pragma unroll
        for (int off = 32; off > 0; off >>= 1) ls += __shfl_down(ls, off, 64);
        if (l == 0) lred[w] = ls;
    }
    __syncthreads();
    if (t == 0)
        partial[blockIdx.x] = __fadd_rn(__fadd_rn(lred[0], lred[1]),
                                        __fadd_rn(lred[2], lred[3]));
}

// ---------------------------------------------------------------------------
__global__ __launch_bounds__(256) void vq_final(const float* __restrict__ partial,
                                                float* __restrict__ out) {
    __shared__ float s[256];
    const int t = threadIdx.x;
    float a = 0.0f;
#pragma unroll
    for (int i = 0; i < 8; ++i) a += partial[t + 256 * i];
    s[t] = a;
    __syncthreads();
    for (int off = 128; off > 0; off >>= 1) {
        if (t < off) s[t] += s[t + off];
        __syncthreads();
    }
    if (t == 0) out[LOSS_OFF] = 0.25f * s[0] / (float)Q_ELEMS;
}

// ---------------------------------------------------------------------------
extern "C" void kernel_launch(void* const* d_in, const int* in_sizes, int n_in,
                              void* d_out, int out_size, void* d_ws, size_t ws_size,
                              hipStream_t stream) {
    const float* in  = (const float*)d_in[0];
    const float* emb = (const float*)d_in[1];
    float* out = (float*)d_out;
    float* ws  = (float*)d_ws;
    float*  partial = ws;                       // 2048 floats
    float*  e2      = ws + 2048;                // 1024 floats
    ushort* ebf     = (ushort*)(ws + 3072);     // 65536 ushorts (128 KB)

    vq_prep<<<4, 256, 0, stream>>>(emb, e2, ebf);
    vq_main<<<MAIN_BLOCKS, 256, 0, stream>>>(in, emb, e2, ebf, out, partial);
    vq_final<<<1, 256, 0, stream>>>(partial, out);
}

// Round 4
// 131.866 us; speedup vs baseline: 3.1008x; 1.1216x over previous
//
#include <hip/hip_runtime.h>
#include <math.h>

// Problem constants
#define NB     32
#define DIM    64
#define HW     4096
#define DHW    (DIM * HW)           // 262144
#define N_ROWS (NB * HW)            // 131072
#define K_CODES 1024

#define Q_ELEMS  (NB * DIM * HW)    // 8388608
#define LOSS_OFF Q_ELEMS
#define IDX_OFF  (Q_ELEMS + 1)

#define ROWS       64               // rows per block
#define MAIN_BLOCKS (N_ROWS / ROWS) // 2048
#define MARGIN     6e-3f
#define CAND_CAP   64

typedef __attribute__((ext_vector_type(8))) short short8;
typedef __attribute__((ext_vector_type(4))) float f32x4;

// ws layout (floats): [0..2048) loss partials, [2048..3072) e2 table,
// then 65536 ushorts (128KB) of bf16 codebook.

__device__ __forceinline__ ushort f2bf_rne(float f) {
    unsigned u = __float_as_uint(f);
    u = (u + 0x7FFFu + ((u >> 16) & 1u)) >> 16;
    return (ushort)u;
}

// ---------------------------------------------------------------------------
// Prep: e2[k] (numpy pairwise-8 order, also used by exact rescore) + bf16 codebook.
__global__ void vq_prep(const float* __restrict__ emb, float* __restrict__ e2out,
                        ushort* __restrict__ ebf) {
    int k = blockIdx.x * blockDim.x + threadIdx.x;
    if (k >= K_CODES) return;
    const float* e = emb + k * DIM;
    float r[8];
#pragma unroll
    for (int j = 0; j < 8; ++j) r[j] = __fmul_rn(e[j], e[j]);
#pragma unroll
    for (int m = 1; m < 8; ++m) {
#pragma unroll
        for (int j = 0; j < 8; ++j)
            r[j] = __fadd_rn(r[j], __fmul_rn(e[8 * m + j], e[8 * m + j]));
    }
    e2out[k] = __fadd_rn(__fadd_rn(__fadd_rn(r[0], r[1]), __fadd_rn(r[2], r[3])),
                         __fadd_rn(__fadd_rn(r[4], r[5]), __fadd_rn(r[6], r[7])));
    ushort* eb = ebf + k * DIM;
#pragma unroll
    for (int d = 0; d < DIM; ++d) eb[d] = f2bf_rne(e[d]);
}

// ---------------------------------------------------------------------------
// Main: 64 rows x 1024 codes per block.
//  Stage X as [d][r] via global_load_lds; MFMA filter (2 passes) + exact rescore.
//  launch_bounds (256,4): 128-VGPR budget -> no scratch spill (round-3 lesson).
__global__ __launch_bounds__(256, 4) void vq_main(
    const float* __restrict__ in, const float* __restrict__ emb,
    const float* __restrict__ e2, const ushort* __restrict__ ebf,
    float* __restrict__ out, float* __restrict__ partial)
{
    __shared__ __align__(16) float Xf[DIM][ROWS];        // 16 KB, [d][r]
    __shared__ float x2s[ROWS];
    __shared__ float wmin[4][ROWS];
    __shared__ float minap[ROWS];
    __shared__ unsigned cnt[ROWS];
    __shared__ ushort cand[ROWS][CAND_CAP];              // 8 KB
    __shared__ int idxs[ROWS];
    __shared__ float lred[4];

    const int t   = threadIdx.x;
    const int w   = t >> 6;
    const int l   = t & 63;
    const int b   = blockIdx.x >> 6;
    const int hw0 = (blockIdx.x & 63) * ROWS;
    const long n0 = (long)b * HW + hw0;
    const float* inb = in + (size_t)b * DHW + hw0;

    // ---- Stage X[d][r] via async global->LDS (linear dest, zero conflicts) --
    {
        const int dl = l >> 4;            // d offset within 4-line packet
        const int c4 = (l & 15) * 4;      // hw offset (floats)
#pragma unroll
        for (int i = 0; i < 4; ++i) {
            const int d0 = w * 16 + i * 4;                 // wave-uniform
            const float* src = inb + (size_t)(d0 + dl) * HW + c4;
            __builtin_amdgcn_global_load_lds(
                (const __attribute__((address_space(1))) void*)src,
                (__attribute__((address_space(3))) void*)&Xf[d0][0],
                16, 0, 0);
        }
        if (t < ROWS) cnt[t] = 0;
    }
    __syncthreads();

    // ---- x2 per row (numpy pairwise-8, bit-identical to round-1 kernel) ----
    if (t < ROWS) {
        float r8[8];
#pragma unroll
        for (int j = 0; j < 8; ++j) {
            const float v = Xf[j][t];
            r8[j] = __fmul_rn(v, v);
        }
#pragma unroll
        for (int m = 1; m < 8; ++m) {
#pragma unroll
            for (int j = 0; j < 8; ++j) {
                const float v = Xf[8 * m + j][t];
                r8[j] = __fadd_rn(r8[j], __fmul_rn(v, v));
            }
        }
        x2s[t] = __fadd_rn(__fadd_rn(__fadd_rn(r8[0], r8[1]), __fadd_rn(r8[2], r8[3])),
                           __fadd_rn(__fadd_rn(r8[4], r8[5]), __fadd_rn(r8[6], r8[7])));
    }

    // ---- A fragments in registers (bf16, same f2bf_rne values as before) ---
    const int lg  = l >> 4;
    const int l15 = l & 15;
    short8 afr[4][2];
#pragma unroll
    for (int rfi = 0; rfi < 4; ++rfi) {
#pragma unroll
        for (int kf = 0; kf < 2; ++kf) {
            const int r  = rfi * 16 + l15;
            const int d0 = (kf * 4 + lg) * 8;
            short8 a;
#pragma unroll
            for (int j = 0; j < 8; ++j) a[j] = (short)f2bf_rne(Xf[d0 + j][r]);
            afr[rfi][kf] = a;
        }
    }

    // ---- Pass 1: per-row min of approx score -------------------------------
    float vmin[4][4];
#pragma unroll
    for (int i = 0; i < 4; ++i)
#pragma unroll
        for (int j = 0; j < 4; ++j) vmin[i][j] = INFINITY;

    for (int iter = 0; iter < 4; ++iter) {
        const int cw = iter * 256 + w * 64;
#pragma unroll
        for (int cfi = 0; cfi < 4; ++cfi) {
            const int code = cw + cfi * 16 + l15;
            const short8 b0 = *(const short8*)(ebf + code * DIM + lg * 8);
            const short8 b1 = *(const short8*)(ebf + code * DIM + 32 + lg * 8);
            const float e2c = e2[code];
#pragma unroll
            for (int rfi = 0; rfi < 4; ++rfi) {
                f32x4 c = {0.f, 0.f, 0.f, 0.f};
                c = __builtin_amdgcn_mfma_f32_16x16x32_bf16(afr[rfi][0], b0, c, 0, 0, 0);
                c = __builtin_amdgcn_mfma_f32_16x16x32_bf16(afr[rfi][1], b1, c, 0, 0, 0);
#pragma unroll
                for (int j = 0; j < 4; ++j) {
                    const float av = __fmaf_rn(-2.0f, c[j], e2c);
                    vmin[rfi][j] = fminf(vmin[rfi][j], av);
                }
            }
        }
    }
#pragma unroll
    for (int m = 1; m < 16; m <<= 1) {
#pragma unroll
        for (int rfi = 0; rfi < 4; ++rfi)
#pragma unroll
            for (int j = 0; j < 4; ++j)
                vmin[rfi][j] = fminf(vmin[rfi][j], __shfl_xor(vmin[rfi][j], m, 64));
    }
    if (l15 == 0) {
#pragma unroll
        for (int rfi = 0; rfi < 4; ++rfi)
#pragma unroll
            for (int j = 0; j < 4; ++j)
                wmin[w][rfi * 16 + lg * 4 + j] = vmin[rfi][j];
    }
    __syncthreads();
    if (t < ROWS)
        minap[t] = fminf(fminf(wmin[0][t], wmin[1][t]),
                         fminf(wmin[2][t], wmin[3][t])) + MARGIN;
    __syncthreads();

    // ---- Pass 2: candidate collection --------------------------------------
    float bound[4][4];
#pragma unroll
    for (int rfi = 0; rfi < 4; ++rfi)
#pragma unroll
        for (int j = 0; j < 4; ++j)
            bound[rfi][j] = minap[rfi * 16 + lg * 4 + j];

    for (int iter = 0; iter < 4; ++iter) {
        const int cw = iter * 256 + w * 64;
#pragma unroll
        for (int cfi = 0; cfi < 4; ++cfi) {
            const int code = cw + cfi * 16 + l15;
            const short8 b0 = *(const short8*)(ebf + code * DIM + lg * 8);
            const short8 b1 = *(const short8*)(ebf + code * DIM + 32 + lg * 8);
            const float e2c = e2[code];
#pragma unroll
            for (int rfi = 0; rfi < 4; ++rfi) {
                f32x4 c = {0.f, 0.f, 0.f, 0.f};
                c = __builtin_amdgcn_mfma_f32_16x16x32_bf16(afr[rfi][0], b0, c, 0, 0, 0);
                c = __builtin_amdgcn_mfma_f32_16x16x32_bf16(afr[rfi][1], b1, c, 0, 0, 0);
#pragma unroll
                for (int j = 0; j < 4; ++j) {
                    const float av = __fmaf_rn(-2.0f, c[j], e2c);
                    if (av <= bound[rfi][j]) {
                        const int row = rfi * 16 + lg * 4 + j;
                        const unsigned slot = atomicAdd(&cnt[row], 1u);
                        if (slot < CAND_CAP) cand[row][slot] = (ushort)code;
                    }
                }
            }
        }
    }
    __syncthreads();

    // ---- Exact fp32 rescore, 4 lanes per row (replicated np op order) ------
    {
        const int q = t & 3;
        const int r = t >> 2;
        int nc = (int)cnt[r];
        if (nc > CAND_CAP) nc = CAND_CAP;
        const float x2v = x2s[r];
        float best = INFINITY;
        int   bk   = K_CODES;
        for (int ci = q; ci < nc; ci += 4) {
            const int k = cand[r][ci];
            const float* ek = emb + k * DIM;
            float dot = 0.0f;
#pragma unroll
            for (int dd = 0; dd < DIM; dd += 4) {
                const float4 ev = *(const float4*)(ek + dd);
                dot = __fmaf_rn(Xf[dd + 0][r], ev.x, dot);
                dot = __fmaf_rn(Xf[dd + 1][r], ev.y, dot);
                dot = __fmaf_rn(Xf[dd + 2][r], ev.z, dot);
                dot = __fmaf_rn(Xf[dd + 3][r], ev.w, dot);
            }
            const float dist = __fadd_rn(__fadd_rn(x2v, e2[k]), -2.0f * dot);
            if (dist < best || (dist == best && k < bk)) { best = dist; bk = k; }
        }
#pragma unroll
        for (int m = 1; m < 4; m <<= 1) {
            const float ob = __shfl_xor(best, m, 64);
            const int   ok = __shfl_xor(bk,   m, 64);
            if (ob < best || (ob == best && ok < bk)) { best = ob; bk = ok; }
        }
        if (q == 0) idxs[r] = bk;
    }
    __syncthreads();

    // ---- coalesced index writes (wave 0) -----------------------------------
    if (t < ROWS) out[IDX_OFF + n0 + t] = (float)idxs[t];

    // ---- quantized_st writes + fused loss (all 256 threads) ----------------
    {
        const int r  = l;          // row = lane (coalesced stores)
        const int dg = w;          // wave covers 16 d-lines
        const float* eq = emb + idxs[r] * DIM + dg * 16;
        float* ob = out + (size_t)b * DHW + hw0 + r;
        float ls = 0.0f;
#pragma unroll
        for (int i = 0; i < 4; ++i) {
            const float4 qv = *(const float4*)(eq + i * 4);
            const float qa[4] = {qv.x, qv.y, qv.z, qv.w};
#pragma unroll
            for (int c2 = 0; c2 < 4; ++c2) {
                const int d = dg * 16 + i * 4 + c2;
                const float xv = Xf[d][r];
                const float df = __fsub_rn(qa[c2], xv);
                ls = __fadd_rn(ls, __fmul_rn(df, df));
                ob[(size_t)d * HW] = __fadd_rn(xv, df);
            }
        }
#pragma unroll
        for (int off = 32; off > 0; off >>= 1) ls += __shfl_down(ls, off, 64);
        if (l == 0) lred[w] = ls;
    }
    __syncthreads();
    if (t == 0)
        partial[blockIdx.x] = __fadd_rn(__fadd_rn(lred[0], lred[1]),
                                        __fadd_rn(lred[2], lred[3]));
}

// ---------------------------------------------------------------------------
__global__ __launch_bounds__(256) void vq_final(const float* __restrict__ partial,
                                                float* __restrict__ out) {
    __shared__ float s[256];
    const int t = threadIdx.x;
    float a = 0.0f;
#pragma unroll
    for (int i = 0; i < 8; ++i) a += partial[t + 256 * i];
    s[t] = a;
    __syncthreads();
    for (int off = 128; off > 0; off >>= 1) {
        if (t < off) s[t] += s[t + off];
        __syncthreads();
    }
    if (t == 0) out[LOSS_OFF] = 0.25f * s[0] / (float)Q_ELEMS;
}

// ---------------------------------------------------------------------------
extern "C" void kernel_launch(void* const* d_in, const int* in_sizes, int n_in,
                              void* d_out, int out_size, void* d_ws, size_t ws_size,
                              hipStream_t stream) {
    const float* in  = (const float*)d_in[0];
    const float* emb = (const float*)d_in[1];
    float* out = (float*)d_out;
    float* ws  = (float*)d_ws;
    float*  partial = ws;                       // 2048 floats
    float*  e2      = ws + 2048;                // 1024 floats
    ushort* ebf     = (ushort*)(ws + 3072);     // 65536 ushorts (128 KB)

    vq_prep<<<4, 256, 0, stream>>>(emb, e2, ebf);
    vq_main<<<MAIN_BLOCKS, 256, 0, stream>>>(in, emb, e2, ebf, out, partial);
    vq_final<<<1, 256, 0, stream>>>(partial, out);
}